// Round 1
// 145.676 us; speedup vs baseline: 1.0489x; 1.0489x over previous
//
#include <hip/hip_runtime.h>

#define MA 64
#define F 128
#define NF 16
#define HID 512
#define LDUB 144    // ub row stride BYTES (128 fp8 + 16 pad)
#define LDWB 144    // wL row stride bytes (64 bf16 + 8 pad elems)
#define LDT1B 1040  // t1 row stride bytes (512 bf16 + 8 pad elems)
// double-buffer base offsets (bytes)
#define UB0 0
#define UB1 9216
#define WL0 18432
#define WL1 27648

typedef float  float4v __attribute__((ext_vector_type(4)));
typedef short  short8  __attribute__((ext_vector_type(8)));
typedef int    int8v   __attribute__((ext_vector_type(8)));

// pack two fp32 -> (bf16(y)<<16)|bf16(x), round-half-up via +0x8000 then v_perm
static __device__ __forceinline__ unsigned int pack2bf(float x, float y) {
    unsigned int a = __float_as_uint(x) + 0x8000u;
    unsigned int b = __float_as_uint(y) + 0x8000u;
    return __builtin_amdgcn_perm(b, a, 0x07060302u);
}
static __device__ __forceinline__ unsigned short f2bf1(float x) {
    return (unsigned short)((__float_as_uint(x) + 0x8000u) >> 16);
}
// pack 4 fp32 -> 4 fp8 e4m3 (RNE, saturating) in one dword
static __device__ __forceinline__ unsigned int pk4fp8(float a, float b, float c, float d) {
    int p = __builtin_amdgcn_cvt_pk_fp8_f32(a, b, 0, false);
    p = __builtin_amdgcn_cvt_pk_fp8_f32(c, d, p, true);
    return (unsigned int)p;
}

// lgkm-only barrier: LDS producer/consumer sync WITHOUT draining vmcnt, so
// global prefetches (afr / aw2r) stay in flight across the rendezvous.
// Cross-wave data moves only through LDS -> lgkmcnt(0) is sufficient.
#define LGKM_BAR() do {                                        \
    asm volatile("s_waitcnt lgkmcnt(0)" ::: "memory");         \
    __builtin_amdgcn_s_barrier();                              \
    asm volatile("" ::: "memory");                             \
} while (0)

// ---- Pack W1 as fp8 MX A-frags (16x16x128) of W1^T; W2 as bf16 A-frags
// (16x16x32) of W2^T. Direct gather. (unchanged)
__global__ void pack_frags(const float* __restrict__ W1, const float* __restrict__ W2,
                           unsigned char* __restrict__ w1p, unsigned short* __restrict__ w2p) {
    int gid  = blockIdx.x * 4 + (threadIdx.x >> 6);
    int lane = threadIdx.x & 63;
    int arow = lane & 15;
    int kq   = lane >> 4;
    if (gid < 544) {                           // W1: kt (17 over K=2176, 128 each) x jt (32)
        int kt = gid >> 5, jt = gid & 31;
        const float* base = W1 + (size_t)(kt * 128 + kq * 32) * HID + jt * 16 + arow;
        unsigned int o[8];
        #pragma unroll
        for (int p = 0; p < 8; p++)
            o[p] = pk4fp8(base[(p * 4 + 0) * HID], base[(p * 4 + 1) * HID],
                          base[(p * 4 + 2) * HID], base[(p * 4 + 3) * HID]);
        unsigned char* dst = w1p + ((size_t)gid * 64 + lane) * 32;
        *(uint4*)dst        = (uint4){o[0], o[1], o[2], o[3]};
        *(uint4*)(dst + 16) = (uint4){o[4], o[5], o[6], o[7]};
    } else if (gid < 544 + 128) {              // W2: kt (16 over J=512) x mt (8 over 128)
        int g2 = gid - 544;
        int kt = g2 >> 3, mt = g2 & 7;
        const float* base = W2 + (size_t)(kt * 32 + kq * 8) * F + mt * 16 + arow;
        short8 o;
        #pragma unroll
        for (int j = 0; j < 8; j++) o[j] = (short)f2bf1(base[j * F]);
        *(short8*)(w2p + ((size_t)g2 * 64 + lane) * 8) = o;
    }
}

// ---- Main fused kernel: ONE molecule per block, 512 threads = 8 waves ----
// launch_bounds(512,2) = 2 waves/SIMD = 1 block/CU, 256-reg budget/wave.
// LDS: ub dbuf @0/9216, wL dbuf @18432/27648 (36864 B live in main loop);
// t1 bf16 full (64 x 1040 = 66560 B) overlays from 0 during GEMM2.
// Main loop: ONE lgkm-only barrier per filter iteration (double-buffered
// ub + wL; writes always target the opposite buffer from this iter's reads).
__launch_bounds__(512, 2)
__global__ void node_conv_mfma(const int* __restrict__ z, const float* __restrict__ rr,
        const float* __restrict__ h, const float* __restrict__ dist,
        const float* __restrict__ wid, const float* __restrict__ b1,
        const float* __restrict__ b2,
        const unsigned char* __restrict__ w1p, const unsigned short* __restrict__ w2p,
        float* __restrict__ out) {
    const int n = blockIdx.x;                  // molecule index
    const int tid = threadIdx.x;
    const int lane = tid & 63;
    const int wave = tid >> 6;
    const int arow = lane & 15;
    const int quad = lane >> 4;
    const int kgrp = quad * 8;

    __shared__ __attribute__((aligned(16))) unsigned char lds[66560];
    __shared__ float r_lds[MA][5];             // xyz + mask, stride-5 (bank spread)

    const int N = gridDim.x;
    const float* hg = h + (size_t)n * MA * F;

    // ---- z / r passthrough + r/mask staging ----
    if (tid < MA) {
        int zi = z[n * MA + tid];
        out[(size_t)n * MA + tid] = (float)zi;
        r_lds[tid][0] = rr[(n * MA + tid) * 3 + 0];
        r_lds[tid][1] = rr[(n * MA + tid) * 3 + 1];
        r_lds[tid][2] = rr[(n * MA + tid) * 3 + 2];
        r_lds[tid][3] = (zi > -1) ? 1.0f : 0.0f;
    }
    if (tid < MA * 3)
        out[(size_t)N * MA + (size_t)n * MA * 3 + tid] = rr[(size_t)n * MA * 3 + tid];

    // ---- stage h -> ub0 (row-major fp8) ----
    for (int i = tid; i < MA * F / 4; i += 512) {
        float4 v = ((const float4*)hg)[i];
        int a = i >> 5, c4 = (i & 31) * 4;
        *(unsigned int*)&lds[UB0 + a * LDUB + c4] = pk4fp8(v.x, v.y, v.z, v.w);
    }
    // ---- hT A-fragments held in registers (bf16): lane holds h[b][c], c = wave*16+arow ----
    short8 ah[2];
    {
        int c = wave * 16 + arow;
        #pragma unroll
        for (int ks2 = 0; ks2 < 2; ks2++)
            #pragma unroll
            for (int j = 0; j < 8; j++)
                ah[ks2][j] = (short)f2bf1(hg[(size_t)(ks2 * 32 + kgrp + j) * F + c]);
    }
    __syncthreads();                           // r_lds + ub0 staged h visible (full drain, once)

    // ---- per-thread pairwise distances, mask folded in ----
    const int wa = tid >> 3;
    const int wb0 = (tid & 7) * 8;
    float dpre[8];
    {
        float ax = r_lds[wa][0], ay = r_lds[wa][1], az = r_lds[wa][2];
        float am = r_lds[wa][3];
        #pragma unroll
        for (int j = 0; j < 8; j++) {
            float dx = ax - r_lds[wb0 + j][0];
            float dy = ay - r_lds[wb0 + j][1];
            float dz = az - r_lds[wb0 + j][2];
            float d = sqrtf(dx * dx + dy * dy + dz * dz + 1e-12f);
            float mm = am * r_lds[wb0 + j][3];
            dpre[j] = d + (1.0f - mm) * 1e4f;
        }
    }

    // ---- prime: w filter 0 -> wL0 (bf16), A-frags for seg 0 ----
    {
        float mu = dist[0];
        float isg = 1.0f / wid[0];
        float e[8];
        #pragma unroll
        for (int j = 0; j < 8; j++) {
            float t = dpre[j] - mu;
            e[j] = 5.0f * __expf(-t * t * isg);
        }
        uint4 wp = { pack2bf(e[0], e[1]), pack2bf(e[2], e[3]),
                     pack2bf(e[4], e[5]), pack2bf(e[6], e[7]) };
        *(uint4*)&lds[WL0 + wa * LDWB + wb0 * 2] = wp;
    }
    int8v afr[4];                              // MX A-frags: 32 B/lane each
    #pragma unroll
    for (int mt = 0; mt < 4; mt++)
        afr[mt] = *(const int8v*)(w1p + ((size_t)((wave * 4 + mt) * 64 + lane)) * 32);
    LGKM_BAR();                                // w0 + ub0 visible; afr loads ride through

    const float4v zf = {0.f, 0.f, 0.f, 0.f};
    float4v acc[4][4];                         // [j-tile][a-tile] = 64 AGPRs
    #pragma unroll
    for (int i = 0; i < 4; i++)
        #pragma unroll
        for (int jv = 0; jv < 4; jv++) acc[i][jv] = zf;

    // ---- main loop: 17 K-segments of 128, ONE barrier per iteration.
    //  iter f: GEMM1 seg f (reads ub[f&1]) -> afr(f+1) prefetch (global, rides
    //  across barriers) -> u-GEMM u_f = hT @ w_f (reads wL[f&1]) -> pack ->
    //  write u_f -> ub[(f+1)&1]; exp w_{f+1} -> wL[(f+1)&1]  -> LGKM_BAR
    for (int f = 0; f <= NF; f++) {
        const int sel = f & 1;
        const int ubR = sel ? UB1 : UB0;
        const int ubW = sel ? UB0 : UB1;
        const int wlR = sel ? WL1 : WL0;
        const int wlW = sel ? WL0 : WL1;

        // GEMM1 seg f: one K=128 scale-MFMA per (mt,at); E8M0 scale 127 = 1.0
        #pragma unroll
        for (int at = 0; at < 4; at++) {
            int8v bfr = *(const int8v*)&lds[ubR + (at * 16 + arow) * LDUB + quad * 32];
            #pragma unroll
            for (int mt = 0; mt < 4; mt++)
                acc[mt][at] = __builtin_amdgcn_mfma_scale_f32_16x16x128_f8f6f4(
                    afr[mt], bfr, acc[mt][at], 0, 0, 0, 127, 0, 127);
        }

        if (f < NF) {
            // prefetch A-frags for seg f+1 (afr regs dead here; loads stay in
            // flight across the lgkm-only barrier, completed by the compiler's
            // vmcnt wait at next iter's first MFMA)
            const unsigned char* pN = w1p + ((size_t)(((f + 1) * 32 + wave * 4) * 64 + lane)) * 32;
            #pragma unroll
            for (int mt = 0; mt < 4; mt++) afr[mt] = *(const int8v*)(pN + mt * 2048);

            // u-GEMM: u_f^T = hT @ w_f (bf16, w symmetric)
            float4v ud[4];
            #pragma unroll
            for (int at = 0; at < 4; at++) ud[at] = zf;
            #pragma unroll
            for (int ks2 = 0; ks2 < 2; ks2++)
                #pragma unroll
                for (int at = 0; at < 4; at++) {
                    short8 bw = *(const short8*)&lds[wlR + (at * 16 + arow) * LDWB + (ks2 * 32 + kgrp) * 2];
                    ud[at] = __builtin_amdgcn_mfma_f32_16x16x32_bf16(ah[ks2], bw, ud[at], 0, 0, 0);
                }
            // pack + store u_f into the WRITE buffer (no barrier needed first:
            // its readers finished before the previous iteration's barrier)
            #pragma unroll
            for (int at = 0; at < 4; at++) {
                unsigned int udp = pk4fp8(ud[at][0], ud[at][1], ud[at][2], ud[at][3]);
                *(unsigned int*)&lds[ubW + (at * 16 + arow) * LDUB + wave * 16 + quad * 4] = udp;
            }

            if (f <= NF - 2) {                 // exp w_{f+1} -> write buffer
                float mu = dist[f + 1];
                float isg = 1.0f / wid[f + 1];
                float e[8];
                #pragma unroll
                for (int j = 0; j < 8; j++) {
                    float t = dpre[j] - mu;
                    e[j] = 5.0f * __expf(-t * t * isg);
                }
                uint4 wp = { pack2bf(e[0], e[1]), pack2bf(e[2], e[3]),
                             pack2bf(e[4], e[5]), pack2bf(e[6], e[7]) };
                *(uint4*)&lds[wlW + wa * LDWB + wb0 * 2] = wp;
            }
        }
        LGKM_BAR();                            // u_f + w_{f+1} visible / final: ub reads drained
    }

    // ---- GEMM2 (bf16): out = h + 0.1*mask*(silu(t1) @ W2 + b2) ----
    // Single pass over full t1 (64 x 512, overlays ub/wL). All 16 W2 A-frags
    // preloaded to registers (64 VGPR, ~96 spare) so loads hide under the
    // silu/pack VALU + barrier; the MFMA loop then has zero global loads.
    float4 b1v[4];
    #pragma unroll
    for (int mt = 0; mt < 4; mt++)
        b1v[mt] = *(const float4*)&b1[wave * 64 + mt * 16 + quad * 4];

    short8 aw2r[16];
    #pragma unroll
    for (int ks = 0; ks < 16; ks++)
        aw2r[ks] = *(const short8*)(w2p + ((size_t)(ks * 8 + wave) * 64 + lane) * 8);

    #pragma unroll
    for (int mt = 0; mt < 4; mt++) {
        #pragma unroll
        for (int at = 0; at < 4; at++) {
            float xs[4];
            #pragma unroll
            for (int r = 0; r < 4; r++) {
                float x = acc[mt][at][r] + ((const float*)&b1v[mt])[r];
                xs[r] = x / (1.0f + __expf(-x));
            }
            uint2 pv = { pack2bf(xs[0], xs[1]), pack2bf(xs[2], xs[3]) };
            *(uint2*)&lds[(at * 16 + arow) * LDT1B + (wave * 64 + mt * 16 + quad * 4) * 2] = pv;
        }
    }
    LGKM_BAR();                                // full t1 visible; aw2r rides through

    float4v g2[4];
    const float4v zf2 = {0.f, 0.f, 0.f, 0.f};
    #pragma unroll
    for (int n2 = 0; n2 < 4; n2++) g2[n2] = zf2;
    #pragma unroll
    for (int ks = 0; ks < 16; ks++) {
        #pragma unroll
        for (int n2 = 0; n2 < 4; n2++) {
            short8 bt = *(const short8*)&lds[(n2 * 16 + arow) * LDT1B + (ks * 32 + kgrp) * 2];
            g2[n2] = __builtin_amdgcn_mfma_f32_16x16x32_bf16(aw2r[ks], bt, g2[n2], 0, 0, 0);
        }
    }

    // D[m=c][n=a]: a = n2*16+arow, c = wave*16+quad*4 + r
    float* outh = out + (size_t)N * MA * 4 + (size_t)n * MA * F;
    const int c0 = wave * 16 + quad * 4;
    float4 b2v = *(const float4*)&b2[c0];
    #pragma unroll
    for (int n2 = 0; n2 < 4; n2++) {
        int a = n2 * 16 + arow;
        float m = r_lds[a][3] * 0.1f;
        float4 hv = *(const float4*)&hg[a * F + c0];
        float4 res;
        res.x = hv.x + (g2[n2][0] + b2v.x) * m;
        res.y = hv.y + (g2[n2][1] + b2v.y) * m;
        res.z = hv.z + (g2[n2][2] + b2v.z) * m;
        res.w = hv.w + (g2[n2][3] + b2v.w) * m;
        *(float4*)&outh[(size_t)a * F + c0] = res;
    }
}

extern "C" void kernel_launch(void* const* d_in, const int* in_sizes, int n_in,
                              void* d_out, int out_size, void* d_ws, size_t ws_size,
                              hipStream_t stream) {
    const int*   z    = (const int*)d_in[0];
    const float* rr   = (const float*)d_in[1];
    const float* h    = (const float*)d_in[2];
    const float* dist = (const float*)d_in[3];
    const float* wid  = (const float*)d_in[4];
    const float* W1   = (const float*)d_in[5];
    const float* b1   = (const float*)d_in[6];
    const float* W2   = (const float*)d_in[7];
    const float* b2   = (const float*)d_in[8];
    float* out = (float*)d_out;

    int Nmol = in_sizes[0] / MA;                           // 512 molecules

    unsigned char*  w1p = (unsigned char*)d_ws;            // 544*64*32 = 1,114,112 B
    unsigned short* w2p = (unsigned short*)(w1p + (size_t)544 * 64 * 32);  // 128 KB bf16

    pack_frags<<<168, 256, 0, stream>>>(W1, W2, w1p, w2p);
    node_conv_mfma<<<Nmol, 512, 0, stream>>>(z, rr, h, dist, wid, b1, b2, w1p, w2p, out);
}